// Round 4
// baseline (5196.081 us; speedup 1.0000x reference)
//
#include <hip/hip_runtime.h>
#include <math.h>

#define TT 9

// ============================================================================
// proj: C[M,768] = A[M,K] @ W[K,768] + b
// tiles BM=128, BN=128, BK=16; 256 threads; 8x8 microtile
// ============================================================================
__global__ __launch_bounds__(256) void proj_kernel(
    const float* __restrict__ A, int K,
    const float* __restrict__ W, const float* __restrict__ bs, float* __restrict__ C)
{
    __shared__ float As[16][132];   // A tile transposed: As[k][m], padded row
    __shared__ float Ws[16][128];   // W tile: Ws[k][n]

    const int tid = threadIdx.x;
    const int tx = tid & 15, ty = tid >> 4;
    const int m0 = blockIdx.y * 128;
    const int n0 = blockIdx.x * 128;

    float acc[8][8];
    #pragma unroll
    for (int i = 0; i < 8; ++i)
        #pragma unroll
        for (int j = 0; j < 8; ++j) acc[i][j] = 0.f;

    const int ar = tid >> 1;          // 0..127 (A tile row)
    const int ac = (tid & 1) * 8;     // 0 or 8  (A tile col base)
    const int wc = tid >> 4;          // 0..15   (W tile row)
    const int wn = (tid & 15) * 8;    // 0..120  (W tile col base)

    for (int k0 = 0; k0 < K; k0 += 16) {
        #pragma unroll
        for (int j = 0; j < 8; ++j) {
            int k = k0 + ac + j;
            As[ac + j][ar] = (k < K) ? A[(size_t)(m0 + ar) * K + k] : 0.f;
        }
        {
            int k = k0 + wc;
            float4 v0 = make_float4(0.f, 0.f, 0.f, 0.f), v1 = v0;
            if (k < K) {
                const float* wp = W + (size_t)k * 768 + n0 + wn;
                v0 = *(const float4*)(wp);
                v1 = *(const float4*)(wp + 4);
            }
            *(float4*)&Ws[wc][wn]     = v0;
            *(float4*)&Ws[wc][wn + 4] = v1;
        }
        __syncthreads();
        #pragma unroll
        for (int kk = 0; kk < 16; ++kk) {
            float4 a0 = *(const float4*)&As[kk][ty * 8];
            float4 a1 = *(const float4*)&As[kk][ty * 8 + 4];
            float4 w0v = *(const float4*)&Ws[kk][tx * 8];
            float4 w1v = *(const float4*)&Ws[kk][tx * 8 + 4];
            float av[8] = {a0.x, a0.y, a0.z, a0.w, a1.x, a1.y, a1.z, a1.w};
            float wv[8] = {w0v.x, w0v.y, w0v.z, w0v.w, w1v.x, w1v.y, w1v.z, w1v.w};
            #pragma unroll
            for (int i = 0; i < 8; ++i)
                #pragma unroll
                for (int j = 0; j < 8; ++j)
                    acc[i][j] = fmaf(av[i], wv[j], acc[i][j]);
        }
        __syncthreads();
    }

    float bias[8];
    #pragma unroll
    for (int j = 0; j < 8; ++j) bias[j] = bs[n0 + tx * 8 + j];
    #pragma unroll
    for (int i = 0; i < 8; ++i) {
        float* cp = C + (size_t)(m0 + ty * 8 + i) * 768 + n0 + tx * 8;
        float4 o0 = make_float4(acc[i][0] + bias[0], acc[i][1] + bias[1],
                                acc[i][2] + bias[2], acc[i][3] + bias[3]);
        float4 o1 = make_float4(acc[i][4] + bias[4], acc[i][5] + bias[5],
                                acc[i][6] + bias[6], acc[i][7] + bias[7]);
        *(float4*)(cp)     = o0;
        *(float4*)(cp + 4) = o1;
    }
}

// ============================================================================
// GRU: persistent-h kernel, ONE direction per launch. Block owns 16 batch
// rows for all 9 timesteps. Thread tid owns gate unit u=tid: inner-GEMM cols
// {tid, tid+256, tid+512} = (z,r,h) of unit tid.
// y layout [rows, T, 512]; out_off selects fwd [0,256) / bwd [256,512).
// dir=1 iterates t = T-1..0 writing at original position (undoes the double
// reversal in the reference).
// ============================================================================
__global__ __launch_bounds__(256) void gru_kernel(
    const float* __restrict__ xp, const float* __restrict__ U, const float* __restrict__ b,
    const float* __restrict__ h0, float* __restrict__ y, int out_off, int dir)
{
    const float* bi = b + 768;   // recurrent-bias row b[1]

    __shared__ float h[16][256];
    const int tid = threadIdx.x;
    const int r0 = blockIdx.x * 16;

    #pragma unroll
    for (int i = 0; i < 16; ++i)
        h[i][tid] = h0 ? h0[(size_t)(r0 + i) * 256 + tid] : 0.f;

    const float bz = bi[tid], br = bi[tid + 256], bh = bi[tid + 512];
    __syncthreads();

    for (int t = 0; t < TT; ++t) {
        const int te = dir ? (TT - 1 - t) : t;
        float acc0[16], acc1[16], acc2[16];
        #pragma unroll
        for (int i = 0; i < 16; ++i) { acc0[i] = 0.f; acc1[i] = 0.f; acc2[i] = 0.f; }

        for (int k = 0; k < 256; k += 8) {
            float w[8][3];
            #pragma unroll
            for (int kk = 0; kk < 8; ++kk) {
                const float* Ur = U + (size_t)(k + kk) * 768;
                w[kk][0] = Ur[tid];
                w[kk][1] = Ur[tid + 256];
                w[kk][2] = Ur[tid + 512];
            }
            #pragma unroll
            for (int i = 0; i < 16; ++i) {
                float4 hv0 = *(const float4*)&h[i][k];
                float4 hv1 = *(const float4*)&h[i][k + 4];
                float hvv[8] = {hv0.x, hv0.y, hv0.z, hv0.w, hv1.x, hv1.y, hv1.z, hv1.w};
                float s0 = acc0[i], s1 = acc1[i], s2 = acc2[i];
                #pragma unroll
                for (int kk = 0; kk < 8; ++kk) {
                    s0 = fmaf(hvv[kk], w[kk][0], s0);
                    s1 = fmaf(hvv[kk], w[kk][1], s1);
                    s2 = fmaf(hvv[kk], w[kk][2], s2);
                }
                acc0[i] = s0; acc1[i] = s1; acc2[i] = s2;
            }
        }
        __syncthreads();   // all reads of h done before updates
        #pragma unroll
        for (int i = 0; i < 16; ++i) {
            const size_t xb = ((size_t)(r0 + i) * TT + te) * 768;
            float xz = xp[xb + tid];
            float xr = xp[xb + tid + 256];
            float xh = xp[xb + tid + 512];
            float z  = 1.f / (1.f + expf(-(xz + acc0[i] + bz)));
            float r  = 1.f / (1.f + expf(-(xr + acc1[i] + br)));
            float hh = tanhf(xh + r * (acc2[i] + bh));
            float hold = h[i][tid];
            float hn = z * hold + (1.f - z) * hh;
            h[i][tid] = hn;
            y[((size_t)(r0 + i) * TT + te) * 512 + out_off + tid] = hn;
        }
        __syncthreads();   // h fully updated before next step's reads
    }
}

// ============================================================================
// score[row] = tanh(Y[row,:] @ W1 + b1) @ V + bV     (rows = flattened b*T+t)
// ============================================================================
__global__ __launch_bounds__(256) void score_kernel(
    const float* __restrict__ Y, const float* __restrict__ W1, const float* __restrict__ b1,
    const float* __restrict__ V, const float* __restrict__ bV,
    float* __restrict__ score)
{
    __shared__ float ylds[16][512];
    __shared__ float sred[16][256];
    const int tid = threadIdx.x;
    const int r0 = blockIdx.x * 16;

    for (int idx = tid; idx < 16 * 512; idx += 256)
        ylds[idx >> 9][idx & 511] = Y[(size_t)r0 * 512 + idx];
    __syncthreads();

    float acc0[16], acc1[16];
    #pragma unroll
    for (int i = 0; i < 16; ++i) { acc0[i] = 0.f; acc1[i] = 0.f; }

    for (int k = 0; k < 512; k += 8) {
        float w[8][2];
        #pragma unroll
        for (int kk = 0; kk < 8; ++kk) {
            const float* Wr = W1 + (size_t)(k + kk) * 512;
            w[kk][0] = Wr[tid];
            w[kk][1] = Wr[tid + 256];
        }
        #pragma unroll
        for (int i = 0; i < 16; ++i) {
            float4 y0 = *(const float4*)&ylds[i][k];
            float4 y1 = *(const float4*)&ylds[i][k + 4];
            float yv[8] = {y0.x, y0.y, y0.z, y0.w, y1.x, y1.y, y1.z, y1.w};
            float s0 = acc0[i], s1 = acc1[i];
            #pragma unroll
            for (int kk = 0; kk < 8; ++kk) {
                s0 = fmaf(yv[kk], w[kk][0], s0);
                s1 = fmaf(yv[kk], w[kk][1], s1);
            }
            acc0[i] = s0; acc1[i] = s1;
        }
    }
    const float v0 = V[tid], v1 = V[tid + 256];
    const float c0 = b1[tid], c1 = b1[tid + 256];
    #pragma unroll
    for (int i = 0; i < 16; ++i)
        sred[i][tid] = tanhf(acc0[i] + c0) * v0 + tanhf(acc1[i] + c1) * v1;
    __syncthreads();
    const int wave = tid >> 6, lane = tid & 63;
    for (int i = wave * 4; i < wave * 4 + 4; ++i) {
        float s = sred[i][lane] + sred[i][lane + 64] + sred[i][lane + 128] + sred[i][lane + 192];
        #pragma unroll
        for (int off = 32; off > 0; off >>= 1) s += __shfl_down(s, off);
        if (lane == 0) score[r0 + i] = s + bV[0];
    }
}

// ============================================================================
// per-batch-row softmax over T + context = sum_t w_t * Y[b,t,:]; also emits
// attention weights.
// ============================================================================
__global__ __launch_bounds__(64) void softmax_ctx_kernel(
    const float* __restrict__ score, const float* __restrict__ Y,
    float* __restrict__ ctx, float* __restrict__ att)
{
    const int b = blockIdx.x;
    const int lane = threadIdx.x;
    __shared__ float wv[TT];
    float s = (lane < TT) ? score[(size_t)b * TT + lane] : -3.0e38f;
    float m = s;
    #pragma unroll
    for (int off = 32; off > 0; off >>= 1) m = fmaxf(m, __shfl_xor(m, off));
    float e = (lane < TT) ? expf(s - m) : 0.f;
    float sum = e;
    #pragma unroll
    for (int off = 32; off > 0; off >>= 1) sum += __shfl_xor(sum, off);
    float wgt = e / sum;
    if (lane < TT) { att[(size_t)b * TT + lane] = wgt; wv[lane] = wgt; }
    __syncthreads();
    float wr[TT];
    #pragma unroll
    for (int t2 = 0; t2 < TT; ++t2) wr[t2] = wv[t2];
    #pragma unroll
    for (int j = 0; j < 8; ++j) {
        int c = lane + j * 64;
        float a = 0.f;
        #pragma unroll
        for (int t2 = 0; t2 < TT; ++t2)
            a = fmaf(wr[t2], Y[((size_t)b * TT + t2) * 512 + c], a);
        ctx[(size_t)b * 512 + c] = a;
    }
}

// ============================================================================
// fused FC1(relu) + FC2 -> logits [rows,2]
// ============================================================================
__global__ __launch_bounds__(256) void fc_kernel(
    const float* __restrict__ ctx, const float* __restrict__ W1, const float* __restrict__ b1,
    const float* __restrict__ W2, const float* __restrict__ b2,
    float* __restrict__ logits)
{
    __shared__ float clds[16][512];
    const int tid = threadIdx.x;
    const int r0 = blockIdx.x * 16;
    for (int idx = tid; idx < 16 * 512; idx += 256)
        clds[idx >> 9][idx & 511] = ctx[(size_t)r0 * 512 + idx];
    __syncthreads();

    float acc0[16], acc1[16];
    #pragma unroll
    for (int i = 0; i < 16; ++i) { acc0[i] = 0.f; acc1[i] = 0.f; }

    for (int k = 0; k < 512; k += 8) {
        float w[8][2];
        #pragma unroll
        for (int kk = 0; kk < 8; ++kk) {
            const float* Wr = W1 + (size_t)(k + kk) * 512;
            w[kk][0] = Wr[tid];
            w[kk][1] = Wr[tid + 256];
        }
        #pragma unroll
        for (int i = 0; i < 16; ++i) {
            float4 y0 = *(const float4*)&clds[i][k];
            float4 y1 = *(const float4*)&clds[i][k + 4];
            float yv[8] = {y0.x, y0.y, y0.z, y0.w, y1.x, y1.y, y1.z, y1.w};
            float s0 = acc0[i], s1 = acc1[i];
            #pragma unroll
            for (int kk = 0; kk < 8; ++kk) {
                s0 = fmaf(yv[kk], w[kk][0], s0);
                s1 = fmaf(yv[kk], w[kk][1], s1);
            }
            acc0[i] = s0; acc1[i] = s1;
        }
    }
    const float w2a0 = W2[(size_t)tid * 2],         w2a1 = W2[(size_t)tid * 2 + 1];
    const float w2b0 = W2[(size_t)(tid + 256) * 2], w2b1 = W2[(size_t)(tid + 256) * 2 + 1];
    const float c0 = b1[tid], c1 = b1[tid + 256];
    __syncthreads();   // done reading clds; reuse as reduction scratch
    #pragma unroll
    for (int i = 0; i < 16; ++i) {
        float h0 = fmaxf(acc0[i] + c0, 0.f);
        float h1 = fmaxf(acc1[i] + c1, 0.f);
        clds[i][tid * 2]     = fmaf(h0, w2a0, h1 * w2b0);
        clds[i][tid * 2 + 1] = fmaf(h0, w2a1, h1 * w2b1);
    }
    __syncthreads();
    const int wave = tid >> 6, lane = tid & 63;
    for (int i = wave * 4; i < wave * 4 + 4; ++i) {
        float px = clds[i][lane * 2]     + clds[i][(lane + 64) * 2]     + clds[i][(lane + 128) * 2]     + clds[i][(lane + 192) * 2];
        float py = clds[i][lane * 2 + 1] + clds[i][(lane + 64) * 2 + 1] + clds[i][(lane + 128) * 2 + 1] + clds[i][(lane + 192) * 2 + 1];
        #pragma unroll
        for (int off = 32; off > 0; off >>= 1) { px += __shfl_down(px, off); py += __shfl_down(py, off); }
        if (lane == 0) {
            logits[(size_t)(r0 + i) * 2]     = px + b2[0];
            logits[(size_t)(r0 + i) * 2 + 1] = py + b2[1];
        }
    }
}

// ============================================================================
extern "C" void kernel_launch(void* const* d_in, const int* in_sizes, int n_in,
                              void* d_out, int out_size, void* d_ws, size_t ws_size,
                              hipStream_t stream)
{
    const float* peptide = (const float*)d_in[0];
    const float* hidden  = (const float*)d_in[1];
    const float* gW[6] = { (const float*)d_in[2],  (const float*)d_in[5],
                           (const float*)d_in[8],  (const float*)d_in[11],
                           (const float*)d_in[14], (const float*)d_in[17] };
    const float* gU[6] = { (const float*)d_in[3],  (const float*)d_in[6],
                           (const float*)d_in[9],  (const float*)d_in[12],
                           (const float*)d_in[15], (const float*)d_in[18] };
    const float* gB[6] = { (const float*)d_in[4],  (const float*)d_in[7],
                           (const float*)d_in[10], (const float*)d_in[13],
                           (const float*)d_in[16], (const float*)d_in[19] };
    const float* att_W1 = (const float*)d_in[20];
    const float* att_b1 = (const float*)d_in[21];
    const float* att_V  = (const float*)d_in[22];
    const float* att_bV = (const float*)d_in[23];
    const float* fc1_W = (const float*)d_in[24];
    const float* fc1_b = (const float*)d_in[25];
    const float* fc2_W = (const float*)d_in[26];
    const float* fc2_b = (const float*)d_in[27];

    float* out = (float*)d_out;   // [0,8192) logits, [8192,45056) attention weights

    // Pick batch-chunk count so the workspace fits: per chunk we need
    // xp [CB*T,768] + yA,yB [CB*T,512] floats (score/ctx overlap into xp).
    int NC = 1;
    size_t CB = 4096;
    for (; NC <= 32; NC *= 2) {
        CB = 4096 / NC;
        size_t floats = (size_t)CB * TT * 768 + 2 * (size_t)CB * TT * 512;
        if (floats * sizeof(float) <= ws_size) break;
    }
    if (NC > 32) { NC = 32; CB = 128; }  // last resort

    float* ws = (float*)d_ws;
    const size_t NXP = (size_t)CB * TT * 768;
    const size_t NY  = (size_t)CB * TT * 512;
    float* xp = ws;            // input proj, one direction at a time
    float* yA = xp + NXP;      // layer output ping  [CB,T,512]
    float* yB = yA + NY;       // layer output pong
    // score/ctx reuse the xp region (dead after the last gru):
    float* score = xp;                              // [CB*T]
    float* ctx   = xp + (((size_t)CB * TT + 255) & ~(size_t)255);  // [CB,512]

    const int M = (int)CB * TT;          // proj rows per chunk
    dim3 pb(256), pg(6, M / 128);        // proj: N/128 x M/128
    dim3 gb(256), gg((unsigned)CB / 16); // gru: CB/16

    for (int c = 0; c < NC; ++c) {
        const float* pep_c = peptide + (size_t)c * CB * TT * 553;
        const float* hid_c = hidden + (size_t)c * CB * 256;
        float* logits_c = out + (size_t)c * CB * 2;
        float* att_c    = out + 8192 + (size_t)c * CB * TT;

        // layer 1 (K=553, h0 = hidden for both directions)
        proj_kernel<<<pg, pb, 0, stream>>>(pep_c, 553, gW[0], gB[0], xp);
        gru_kernel<<<gg, gb, 0, stream>>>(xp, gU[0], gB[0], hid_c, yA, 0, 0);
        proj_kernel<<<pg, pb, 0, stream>>>(pep_c, 553, gW[1], gB[1], xp);
        gru_kernel<<<gg, gb, 0, stream>>>(xp, gU[1], gB[1], hid_c, yA, 256, 1);
        // layer 2 (K=512, h0 = 0)
        proj_kernel<<<pg, pb, 0, stream>>>(yA, 512, gW[2], gB[2], xp);
        gru_kernel<<<gg, gb, 0, stream>>>(xp, gU[2], gB[2], nullptr, yB, 0, 0);
        proj_kernel<<<pg, pb, 0, stream>>>(yA, 512, gW[3], gB[3], xp);
        gru_kernel<<<gg, gb, 0, stream>>>(xp, gU[3], gB[3], nullptr, yB, 256, 1);
        // layer 3
        proj_kernel<<<pg, pb, 0, stream>>>(yB, 512, gW[4], gB[4], xp);
        gru_kernel<<<gg, gb, 0, stream>>>(xp, gU[4], gB[4], nullptr, yA, 0, 0);
        proj_kernel<<<pg, pb, 0, stream>>>(yB, 512, gW[5], gB[5], xp);
        gru_kernel<<<gg, gb, 0, stream>>>(xp, gU[5], gB[5], nullptr, yA, 256, 1);
        // attention + head
        score_kernel<<<dim3(M / 16), dim3(256), 0, stream>>>(yA, att_W1, att_b1, att_V, att_bV, score);
        softmax_ctx_kernel<<<dim3((unsigned)CB), dim3(64), 0, stream>>>(score, yA, ctx, att_c);
        fc_kernel<<<dim3((unsigned)CB / 16), dim3(256), 0, stream>>>(ctx, fc1_W, fc1_b, fc2_W, fc2_b, logits_c);
    }
}